// Round 4
// baseline (510.941 us; speedup 1.0000x reference)
//
#include <hip/hip_runtime.h>
#include <math.h>

// Problem constants
#define NROWS 65536
#define DDIM  1024
#define NEXP  64
#define BM    64      // rows per block
#define WCHUNK 12288  // shorts per k32-chunk of packed w: 3 splits * 128 n * 32 k

typedef short bf16x8 __attribute__((ext_vector_type(8)));
typedef float f32x4  __attribute__((ext_vector_type(4)));

// round-to-nearest 3-way bf16 split (one-time w prep)
__device__ __forceinline__ void split3(float x, unsigned short& h,
                                       unsigned short& m, unsigned short& l) {
    unsigned u = __float_as_uint(x);
    unsigned r = u + 0x7FFFu + ((u >> 16) & 1u);
    h = (unsigned short)(r >> 16);
    float hf = __uint_as_float(r & 0xFFFF0000u);
    float r1 = x - hf;
    unsigned u2 = __float_as_uint(r1);
    unsigned r2 = u2 + 0x7FFFu + ((u2 >> 16) & 1u);
    m = (unsigned short)(r2 >> 16);
    float mf = __uint_as_float(r2 & 0xFFFF0000u);
    float r3 = r1 - mf;
    unsigned u3 = __float_as_uint(r3);
    unsigned r4 = u3 + 0x7FFFu + ((u3 >> 16) & 1u);
    l = (unsigned short)(r4 >> 16);
}

__device__ __forceinline__ float softplus_f(float x) {
    return fmaxf(x, 0.0f) + log1pf(expf(-fabsf(x)));
}

// Pack weights: wp[chunk][split][n][32] bf16, n = 0..63 route, 64..127 noise.
__global__ void __launch_bounds__(256) prep_w_kernel(
        const float* __restrict__ wr, const float* __restrict__ wn,
        short* __restrict__ wp) {
    int idx = blockIdx.x * 256 + threadIdx.x;   // 0..131071
    int n = idx >> 10;
    int k = idx & 1023;
    float v = (n < NEXP) ? wr[n * DDIM + k] : wn[(n - NEXP) * DDIM + k];
    unsigned short h, m, l;
    split3(v, h, m, l);
    int base = (k >> 5) * WCHUNK + n * 32 + (k & 31);
    wp[base]        = (short)h;
    wp[base + 4096] = (short)m;
    wp[base + 8192] = (short)l;
}

__device__ __forceinline__ void top2_merge(float& v0, int& i0, float& v1, int& i1,
                                           float pv0, int pi0, float pv1, int pi1) {
    bool t0 = (pv0 > v0) || (pv0 == v0 && pi0 < i0);
    if (t0) {
        bool t1 = (v0 > pv1) || (v0 == pv1 && i0 < pi1);
        v1 = t1 ? v0 : pv1; i1 = t1 ? i0 : pi1;
        v0 = pv0; i0 = pi0;
    } else {
        bool t1 = (pv0 > v1) || (pv0 == v1 && pi0 < i1);
        if (t1) { v1 = pv0; i1 = pi0; }
    }
}

__global__ void __launch_bounds__(256, 4) router_kernel(
        const float* __restrict__ x, const short* __restrict__ wp,
        const float* __restrict__ eps, float* __restrict__ out) {
    // LDS used ONLY in the epilogue — the K-loop is barrier-free, pure registers.
    __shared__ float  noisy[BM * 66];
    __shared__ float4 rowout[BM];

    const int tid    = threadIdx.x;
    const int lane   = tid & 63;
    const int wv     = tid >> 6;      // wave 0..3 -> expert col group
    const int lane16 = lane & 15;
    const int quad   = lane >> 4;
    const int blockM = blockIdx.x * BM;
    const int col_r  = wv * 16 + lane16;

    // A-fragment base: row = blockM + mi*16 + lane16, k = kc*32 + quad*8
    const float* xbase = x + (size_t)(blockM + lane16) * DDIM + quad * 8;

    f32x4 acc[4][2];   // [mi][0]=route, [1]=noise
#pragma unroll
    for (int a = 0; a < 4; ++a) { acc[a][0] = (f32x4)0.0f; acc[a][1] = (f32x4)0.0f; }

#pragma unroll 1
    for (int kc = 0; kc < DDIM / 32; ++kc) {
        // B fragments from packed w (768 KB total -> L2-hot)
        const short* wpc = wp + (size_t)kc * WCHUNK + quad * 8;
        bf16x8 Bf[3][2];
#pragma unroll
        for (int s = 0; s < 3; ++s) {
            Bf[s][0] = *(const bf16x8*)(wpc + s * 4096 + col_r * 32);
            Bf[s][1] = *(const bf16x8*)(wpc + s * 4096 + (col_r + 64) * 32);
        }

        // A raw fp32: 8 consecutive k per lane, 2x dwordx4 per mi
        float4 a[4][2];
#pragma unroll
        for (int mi = 0; mi < 4; ++mi) {
            const float* ap = xbase + (size_t)(mi * 16) * DDIM + kc * 32;
            a[mi][0] = *(const float4*)ap;
            a[mi][1] = *(const float4*)(ap + 4);
        }

#pragma unroll
        for (int mi = 0; mi < 4; ++mi) {
            // in-register 3-way truncation split: x = h + m + l + O(2^-24 x)
            bf16x8 Ah, Am, Al;
#pragma unroll
            for (int j = 0; j < 8; ++j) {
                float xv = (j < 4) ? ((const float*)&a[mi][0])[j]
                                   : ((const float*)&a[mi][1])[j - 4];
                unsigned u = __float_as_uint(xv);
                Ah[j] = (short)(u >> 16);
                float r1 = xv - __uint_as_float(u & 0xFFFF0000u);
                unsigned u2 = __float_as_uint(r1);
                Am[j] = (short)(u2 >> 16);
                float r2 = r1 - __uint_as_float(u2 & 0xFFFF0000u);
                Al[j] = (short)(__float_as_uint(r2) >> 16);
            }
#pragma unroll
            for (int ni = 0; ni < 2; ++ni) {
                f32x4 c = acc[mi][ni];
                // small-terms-first: lh, hl, mm, mh, hm, hh
                c = __builtin_amdgcn_mfma_f32_16x16x32_bf16(Al, Bf[0][ni], c, 0, 0, 0);
                c = __builtin_amdgcn_mfma_f32_16x16x32_bf16(Ah, Bf[2][ni], c, 0, 0, 0);
                c = __builtin_amdgcn_mfma_f32_16x16x32_bf16(Am, Bf[1][ni], c, 0, 0, 0);
                c = __builtin_amdgcn_mfma_f32_16x16x32_bf16(Am, Bf[0][ni], c, 0, 0, 0);
                c = __builtin_amdgcn_mfma_f32_16x16x32_bf16(Ah, Bf[1][ni], c, 0, 0, 0);
                c = __builtin_amdgcn_mfma_f32_16x16x32_bf16(Ah, Bf[0][ni], c, 0, 0, 0);
                acc[mi][ni] = c;
            }
        }
    }

    // ---------------- Epilogue ----------------
    // C-frag: row = quad*4 + v, col = lane16  [verified r2/r3]
#pragma unroll
    for (int mi = 0; mi < 4; ++mi)
#pragma unroll
        for (int v = 0; v < 4; ++v) {
            int row = mi * 16 + quad * 4 + v;
            float ev = eps[(size_t)(blockM + row) * NEXP + col_r];
            noisy[row * 66 + col_r] =
                fmaf(ev, softplus_f(acc[mi][1][v]), acc[mi][0][v]);
        }
    __syncthreads();

    // top-2: 4 threads/row scan 16 cols each, merge via shfl_xor(1), shfl_xor(2)
    {
        int row = tid >> 2;
        int sub = tid & 3;
        float v0 = -INFINITY, v1 = -INFINITY;
        int   i0 = 1 << 20,   i1 = 1 << 20;
#pragma unroll
        for (int j = 0; j < 16; ++j) {
            int col = sub * 16 + j;
            float v = noisy[row * 66 + col];
            if (v > v0) { v1 = v0; i1 = i0; v0 = v; i0 = col; }
            else if (v > v1) { v1 = v; i1 = col; }
        }
#pragma unroll
        for (int d = 1; d <= 2; d <<= 1) {
            float pv0 = __shfl_xor(v0, d, 64);
            int   pi0 = __shfl_xor(i0, d, 64);
            float pv1 = __shfl_xor(v1, d, 64);
            int   pi1 = __shfl_xor(i1, d, 64);
            top2_merge(v0, i0, v1, i1, pv0, pi0, pv1, pi1);
        }
        if (sub == 0) {
            float e1  = expf(v1 - v0);
            float inv = 1.0f / (1.0f + e1);
            rowout[row] = make_float4(inv, e1 * inv,
                                      __int_as_float(i0), __int_as_float(i1));
            float* idx_out = out + (size_t)NROWS * NEXP;
            *(float2*)&idx_out[(size_t)(blockM + row) * 2] =
                make_float2((float)i0, (float)i1);
        }
    }
    __syncthreads();

    // coalesced [64][64] output tile write
#pragma unroll
    for (int it = 0; it < 4; ++it) {
        int f  = it * 256 + tid;       // float4 id 0..1023
        int m  = f >> 4;
        int c4 = (f & 15) << 2;
        float4 ro = rowout[m];
        int i0 = __float_as_int(ro.z);
        int i1 = __float_as_int(ro.w);
        float4 o;
        float* op = (float*)&o;
#pragma unroll
        for (int j = 0; j < 4; ++j) {
            int col = c4 + j;
            op[j] = (col == i0) ? ro.x : (col == i1) ? ro.y : 0.0f;
        }
        *(float4*)&out[(size_t)(blockM + m) * NEXP + c4] = o;
    }
}

extern "C" void kernel_launch(void* const* d_in, const int* in_sizes, int n_in,
                              void* d_out, int out_size, void* d_ws, size_t ws_size,
                              hipStream_t stream) {
    const float* x   = (const float*)d_in[0];
    const float* wr  = (const float*)d_in[1];
    const float* wn  = (const float*)d_in[2];
    const float* eps = (const float*)d_in[3];
    float* out = (float*)d_out;
    short* wp  = (short*)d_ws;   // 32 chunks * 12288 shorts = 1.5 MB scratch

    prep_w_kernel<<<dim3(512), dim3(256), 0, stream>>>(wr, wn, wp);
    router_kernel<<<dim3(NROWS / BM), dim3(256), 0, stream>>>(x, wp, eps, out);
}